// Round 3
// baseline (522.596 us; speedup 1.0000x reference)
//
#include <hip/hip_runtime.h>
#include <hip/hip_bf16.h>

typedef __bf16 bf16x8_t __attribute__((ext_vector_type(8)));
typedef __bf16 bf16x4_t __attribute__((ext_vector_type(4)));
typedef float  f32x4_t  __attribute__((ext_vector_type(4)));

#define MFMA_16x16x32_BF16(A, B, C) __builtin_amdgcn_mfma_f32_16x16x32_bf16((A), (B), (C), 0, 0, 0)

static constexpr int B_ = 16;
static constexpr int T_ = 2048;
static constexpr int C_ = 1024;
static constexpr int H_ = 128;
static constexpr long M_ = (long)B_ * T_;   // 32768 rows

// ---------------------------------------------------------------------------
// W transpose: WT[z][h][c] = bf16(W_z[c][h]).  z order: 0=q, 1=k, 2=v.
// Lane h reads 8 consecutive c (coalesced 512B rows), writes one bf16x8.
// ---------------------------------------------------------------------------
__global__ __launch_bounds__(128) void wt_kernel(
    const float* __restrict__ Wq, const float* __restrict__ Wk,
    const float* __restrict__ Wv, __bf16* __restrict__ WT)
{
    const int z = blockIdx.y;
    const float* __restrict__ W = (z == 0) ? Wq : (z == 1) ? Wk : Wv;
    const int h  = threadIdx.x;          // 0..127
    const int c0 = blockIdx.x * 8;
    bf16x8_t v;
    #pragma unroll
    for (int j = 0; j < 8; ++j)
        v[j] = (__bf16)W[(c0 + j) * H_ + h];
    *(bf16x8_t*)&WT[((long)z * H_ + h) * C_ + c0] = v;
}

// ---------------------------------------------------------------------------
// Fused projection: q,k,v = x @ {Wq,Wk,Wv}. x read ONCE (fp32->bf16 inline).
// No LDS, no barriers: B-fragments are direct 16B global loads from WT
// (786 KB, L2-resident, shared by all blocks) -> compiler free to pipeline.
// Block 256 = 4 waves: wave (rowgrp = w&1, colhalf = w>>1) computes
// 32 rows x 64 cols x 3 outputs (acc = 3*2*4 f32x4 = 96 VGPRs).
// q,k out [M][H] bf16; v out transposed [B][H][T] bf16.
// ---------------------------------------------------------------------------
__global__ __launch_bounds__(256) void proj_kernel(
    const float*  __restrict__ x,
    const __bf16* __restrict__ WT,
    __bf16* __restrict__ qo,
    __bf16* __restrict__ ko,
    __bf16* __restrict__ vo)
{
    const int tid  = threadIdx.x;
    const int lane = tid & 63;
    const int w    = tid >> 6;
    const int m16  = lane & 15;
    const int quad = lane >> 4;
    const int koff = quad * 8;

    const int  rowgrp  = w & 1;
    const int  colhalf = w >> 1;
    const long r0 = (long)blockIdx.x * 64 + rowgrp * 32;
    const int  c0 = colhalf * 64;

    f32x4_t acc[3][2][4];
    #pragma unroll
    for (int z = 0; z < 3; ++z)
        #pragma unroll
        for (int mt = 0; mt < 2; ++mt)
            #pragma unroll
            for (int nt = 0; nt < 4; ++nt)
                acc[z][mt][nt] = f32x4_t{0, 0, 0, 0};

    for (int k0 = 0; k0 < C_; k0 += 32) {
        const float* xr0 = &x[(r0 + m16) * C_ + k0 + koff];
        const float* xr1 = &x[(r0 + 16 + m16) * C_ + k0 + koff];
        f32x4_t lo0 = *(const f32x4_t*)xr0, hi0 = *(const f32x4_t*)(xr0 + 4);
        f32x4_t lo1 = *(const f32x4_t*)xr1, hi1 = *(const f32x4_t*)(xr1 + 4);
        bf16x8_t a0, a1;
        #pragma unroll
        for (int j = 0; j < 4; ++j) {
            a0[j] = (__bf16)lo0[j]; a0[4 + j] = (__bf16)hi0[j];
            a1[j] = (__bf16)lo1[j]; a1[4 + j] = (__bf16)hi1[j];
        }
        #pragma unroll
        for (int z = 0; z < 3; ++z) {
            #pragma unroll
            for (int nt = 0; nt < 4; ++nt) {
                bf16x8_t bfr = *(const bf16x8_t*)
                    &WT[((long)z * H_ + c0 + nt * 16 + m16) * C_ + k0 + koff];
                acc[z][0][nt] = MFMA_16x16x32_BF16(a0, bfr, acc[z][0][nt]);
                acc[z][1][nt] = MFMA_16x16x32_BF16(a1, bfr, acc[z][1][nt]);
            }
        }
    }

    // Epilogue. C/D: col = lane&15 (n), row = quad*4 + r (m).
    #pragma unroll
    for (int z = 0; z < 2; ++z) {
        __bf16* __restrict__ o = (z == 0) ? qo : ko;
        #pragma unroll
        for (int mt = 0; mt < 2; ++mt) {
            long rb = r0 + mt * 16 + quad * 4;
            #pragma unroll
            for (int nt = 0; nt < 4; ++nt)
                #pragma unroll
                for (int r = 0; r < 4; ++r)
                    o[(rb + r) * H_ + c0 + nt * 16 + m16] = (__bf16)acc[z][mt][nt][r];
        }
    }
    // v transposed: rows rb..rb+3 are 4 consecutive t within one batch.
    #pragma unroll
    for (int mt = 0; mt < 2; ++mt) {
        long rb = r0 + mt * 16 + quad * 4;
        long bb = rb >> 11;
        long tt = rb & 2047;
        #pragma unroll
        for (int nt = 0; nt < 4; ++nt) {
            bf16x4_t pk;
            #pragma unroll
            for (int r = 0; r < 4; ++r) pk[r] = (__bf16)acc[2][mt][nt][r];
            *(bf16x4_t*)&vo[bb * (H_ * (long)T_) + (c0 + nt * 16 + m16) * (long)T_ + tt] = pk;
        }
    }
}

// ---------------------------------------------------------------------------
// Flash attention, causal, TRANSPOSED score trick. One wave per (b, 16-q tile).
// S^T = K·Q^T  =>  C/D col (lane&15) = q index: row stats need only in-lane
// reduction + 2 shuffles (xor 16/32) instead of 4-step 16-lane reductions.
// P stored [q][k] bf16 in LDS (stride 40, double-buffered) so the PV B-frag
// is a single ds_read_b128. O^T = V^T·P^T with V^T fragments from vT.
// NO barriers: single wave; same-wave LDS ops execute in order; double
// buffering removes the WAR across iterations -> K/V loads pipeline freely.
// Heavy (high-q0) blocks dispatched first via reversed q-tile index.
// ---------------------------------------------------------------------------
__global__ __launch_bounds__(64) void attn_kernel(
    const __bf16* __restrict__ q,   // [B][T][H]
    const __bf16* __restrict__ k,   // [B][T][H]
    const __bf16* __restrict__ vT,  // [B][H][T]
    float* __restrict__ out)        // [B][T][H] fp32
{
    const int b    = blockIdx.y;
    const int q0   = (gridDim.x - 1 - blockIdx.x) * 16;   // heavy tiles first
    const int lane = threadIdx.x;
    const int m16  = lane & 15;
    const int quad = lane >> 4;
    const int koff = quad * 8;

    const __bf16* __restrict__ qb = q  + (long)b * T_ * H_;
    const __bf16* __restrict__ kb = k  + (long)b * T_ * H_;
    const __bf16* __restrict__ vb = vT + (long)b * H_ * T_;

    // Q^T B-fragments: lane n=m16=q holds c = s*32 + quad*8 + j -> 16B loads
    bf16x8_t qfr[4];
    #pragma unroll
    for (int s = 0; s < 4; ++s)
        qfr[s] = *(const bf16x8_t*)&qb[(q0 + m16) * H_ + s * 32 + koff];

    f32x4_t acc[8];                       // O^T tiles: row=h (quad*4+r), col=q (m16)
    #pragma unroll
    for (int i = 0; i < 8; ++i) acc[i] = f32x4_t{0, 0, 0, 0};
    float mrun = -1e30f, lrun = 0.f;      // per-lane stats for q = q0 + m16

    __shared__ __bf16 P16[2][16 * 40];    // [q][k], stride 40, double-buffered
    int parity = 0;

    const float SC = 0.08838834764831845f;   // 1/sqrt(128)
    const int qg = q0 + m16;

    for (int tk0 = 0; tk0 <= q0 + 15; tk0 += 32) {
        // ---- S^T = K Q^T : two 16-krow tiles ----
        f32x4_t s0 = f32x4_t{0,0,0,0}, s1 = f32x4_t{0,0,0,0};
        #pragma unroll
        for (int s = 0; s < 4; ++s) {
            bf16x8_t k0f = *(const bf16x8_t*)&kb[(tk0      + m16) * H_ + s * 32 + koff];
            bf16x8_t k1f = *(const bf16x8_t*)&kb[(tk0 + 16 + m16) * H_ + s * 32 + koff];
            s0 = MFMA_16x16x32_BF16(k0f, qfr[s], s0);
            s1 = MFMA_16x16x32_BF16(k1f, qfr[s], s1);
        }

        // ---- mask + scale; row (=q) stats: local 8 + 2 shuffles ----
        float v0[4], v1[4];
        float mloc = -1e30f;
        #pragma unroll
        for (int r = 0; r < 4; ++r) {
            int kg0 = tk0 + quad * 4 + r;
            v0[r] = (kg0      <= qg) ? s0[r] * SC : -1e30f;
            v1[r] = (kg0 + 16 <= qg) ? s1[r] * SC : -1e30f;
            mloc = fmaxf(mloc, fmaxf(v0[r], v1[r]));
        }
        mloc = fmaxf(mloc, __shfl_xor(mloc, 16, 64));
        mloc = fmaxf(mloc, __shfl_xor(mloc, 32, 64));

        float mnew = fmaxf(mrun, mloc);
        float al   = __expf(mrun - mnew);
        float psum = 0.f;
        __bf16* Pb = &P16[parity][0];
        #pragma unroll
        for (int r = 0; r < 4; ++r) {
            float p0 = __expf(v0[r] - mnew);
            float p1 = __expf(v1[r] - mnew);
            psum += p0 + p1;
            // P[q=m16][k]: k = quad*4+r and 16+quad*4+r
            Pb[m16 * 40 + quad * 4 + r]      = (__bf16)p0;
            Pb[m16 * 40 + 16 + quad * 4 + r] = (__bf16)p1;
        }
        psum += __shfl_xor(psum, 16, 64);
        psum += __shfl_xor(psum, 32, 64);
        mrun = mnew;
        lrun = lrun * al + psum;

        #pragma unroll
        for (int i = 0; i < 8; ++i)
            #pragma unroll
            for (int r = 0; r < 4; ++r)
                acc[i][r] *= al;

        // PV B-frag: lane n=m16=q holds k = quad*8+j -> one ds_read_b128
        bf16x8_t pa = *(const bf16x8_t*)&Pb[m16 * 40 + koff];

        // ---- O^T += V^T P^T : A-frag = vT rows (h), k-dim = t ----
        #pragma unroll
        for (int i = 0; i < 8; ++i) {
            bf16x8_t vv = *(const bf16x8_t*)&vb[(i * 16 + m16) * (long)T_ + tk0 + koff];
            acc[i] = MFMA_16x16x32_BF16(vv, pa, acc[i]);
        }
        parity ^= 1;
    }

    // ---- epilogue: O[q][h] = acc[i][r]/lrun; f32x4 stores ----
    float* __restrict__ ob = out + (long)b * T_ * H_;
    const float inv = 1.f / lrun;
    #pragma unroll
    for (int i = 0; i < 8; ++i) {
        f32x4_t o;
        #pragma unroll
        for (int r = 0; r < 4; ++r) o[r] = acc[i][r] * inv;
        *(f32x4_t*)&ob[(q0 + m16) * H_ + i * 16 + quad * 4] = o;
    }
}

// ---------------------------------------------------------------------------
extern "C" void kernel_launch(void* const* d_in, const int* in_sizes, int n_in,
                              void* d_out, int out_size, void* d_ws, size_t ws_size,
                              hipStream_t stream)
{
    // setup_inputs order: x, Wk, Wq, Wv — all float32
    const float* x  = (const float*)d_in[0];
    const float* Wk = (const float*)d_in[1];
    const float* Wq = (const float*)d_in[2];
    const float* Wv = (const float*)d_in[3];

    // ws: q [M,H] bf16 | k [M,H] bf16 | vT [B][H][T] bf16 | WT [3][H][C] bf16
    __bf16* qws = (__bf16*)d_ws;
    __bf16* kws = qws + M_ * H_;
    __bf16* vws = kws + M_ * H_;
    __bf16* WT  = vws + (long)B_ * H_ * T_;
    float*  out = (float*)d_out;

    wt_kernel  <<<dim3(C_ / 8, 3), 128, 0, stream>>>(Wq, Wk, Wv, WT);
    proj_kernel<<<dim3((int)(M_ / 64)), 256, 0, stream>>>(x, WT, qws, kws, vws);
    attn_kernel<<<dim3(T_ / 16, B_), 64, 0, stream>>>(qws, kws, vws, out);
}

// Round 4
// 445.275 us; speedup vs baseline: 1.1736x; 1.1736x over previous
//
#include <hip/hip_runtime.h>
#include <hip/hip_bf16.h>

typedef __bf16 bf16x8_t __attribute__((ext_vector_type(8)));
typedef __bf16 bf16x4_t __attribute__((ext_vector_type(4)));
typedef float  f32x4_t  __attribute__((ext_vector_type(4)));

#define MFMA_16x16x32_BF16(A, B, C) __builtin_amdgcn_mfma_f32_16x16x32_bf16((A), (B), (C), 0, 0, 0)

static constexpr int B_ = 16;
static constexpr int T_ = 2048;
static constexpr int C_ = 1024;
static constexpr int H_ = 128;
static constexpr long M_ = (long)B_ * T_;   // 32768 rows

// ---------------------------------------------------------------------------
// W transpose: WT[z][h][c] = bf16(W_z[c][h]).  z order: 0=q, 1=k, 2=v.
// Flat view: WT[n][c] with n = z*128 + h  (384 rows x 1024 cols).
// ---------------------------------------------------------------------------
__global__ __launch_bounds__(128) void wt_kernel(
    const float* __restrict__ Wq, const float* __restrict__ Wk,
    const float* __restrict__ Wv, __bf16* __restrict__ WT)
{
    const int z = blockIdx.y;
    const float* __restrict__ W = (z == 0) ? Wq : (z == 1) ? Wk : Wv;
    const int h  = threadIdx.x;          // 0..127
    const int c0 = blockIdx.x * 8;
    bf16x8_t v;
    #pragma unroll
    for (int j = 0; j < 8; ++j)
        v[j] = (__bf16)W[(c0 + j) * H_ + h];
    *(bf16x8_t*)&WT[((long)z * H_ + h) * C_ + c0] = v;
}

// ---------------------------------------------------------------------------
// Fused projection, LDS-tiled for occupancy. x read ONCE (fp32->bf16 inline).
// Grid 1024 blocks x 256 thr (4 waves): block = 32 rows x 384 cols (3 z's).
// Wave w: m-tile = w&1 (16 rows), n-half = w>>1 (12 n-tiles of 16 = 192 cols).
// Per k-step (32): stage x-tile + WT-tile in LDS (stride 40), 12 MFMAs/wave,
// acc = 12 f32x4 = 48 VGPRs -> 4 blocks/CU (LDS 32.5 KB), 16 waves/CU.
// ---------------------------------------------------------------------------
__global__ __launch_bounds__(256) void proj_kernel(
    const float*  __restrict__ x,
    const __bf16* __restrict__ WT,
    __bf16* __restrict__ qo,
    __bf16* __restrict__ ko,
    __bf16* __restrict__ vo)
{
    __shared__ __bf16 XS[32 * 40];    // [row][k]  2.5 KB
    __shared__ __bf16 WS[384 * 40];   // [n][k]   30 KB

    const int tid  = threadIdx.x;
    const int lane = tid & 63;
    const int w    = tid >> 6;
    const int m16  = lane & 15;
    const int quad = lane >> 4;
    const int koff = quad * 8;

    const int  mt = w & 1;
    const int  nh = w >> 1;
    const long r0 = (long)blockIdx.x * 32;

    f32x4_t acc[12];
    #pragma unroll
    for (int nt = 0; nt < 12; ++nt) acc[nt] = f32x4_t{0, 0, 0, 0};

    const int xrow = tid >> 3, xc4 = tid & 7;   // x staging coords

    for (int k0 = 0; k0 < C_; k0 += 32) {
        // stage x-tile: 8 threads/row, 16B fp32 -> 8B bf16 each
        f32x4_t xv = *(const f32x4_t*)&x[(r0 + xrow) * C_ + k0 + xc4 * 4];
        bf16x4_t xb;
        #pragma unroll
        for (int j = 0; j < 4; ++j) xb[j] = (__bf16)xv[j];
        *(bf16x4_t*)&XS[xrow * 40 + xc4 * 4] = xb;

        // stage WT-tile: 384 rows x 32 k, 4 threads/row (64B), 6 chunks/thread
        #pragma unroll
        for (int ch = 0; ch < 6; ++ch) {
            int g = tid + 256 * ch;          // 0..1535
            int n = g >> 2, kc = g & 3;
            *(bf16x8_t*)&WS[n * 40 + kc * 8] =
                *(const bf16x8_t*)&WT[(long)n * C_ + k0 + kc * 8];
        }
        __syncthreads();

        bf16x8_t a = *(const bf16x8_t*)&XS[(mt * 16 + m16) * 40 + koff];
        #pragma unroll
        for (int nt = 0; nt < 12; ++nt) {
            bf16x8_t bfr = *(const bf16x8_t*)&WS[((nh * 12 + nt) * 16 + m16) * 40 + koff];
            acc[nt] = MFMA_16x16x32_BF16(a, bfr, acc[nt]);
        }
        __syncthreads();
    }

    // Epilogue. C/D: col = m16 (n-in-tile), row = quad*4 + r (m-in-tile).
    const long rbase = r0 + mt * 16 + quad * 4;
    #pragma unroll
    for (int nt = 0; nt < 12; ++nt) {
        int ntg = nh * 12 + nt;
        int z   = ntg >> 3;                   // 8 n-tiles per z
        int h   = (ntg & 7) * 16 + m16;
        if (z < 2) {
            __bf16* __restrict__ o = z ? ko : qo;
            #pragma unroll
            for (int r = 0; r < 4; ++r)
                o[(rbase + r) * H_ + h] = (__bf16)acc[nt][r];
        } else {
            // v transposed [b][h][t]; rbase..+3 stay in one batch (32 | 2048)
            long bb = rbase >> 11, tt = rbase & 2047;
            bf16x4_t pk;
            #pragma unroll
            for (int r = 0; r < 4; ++r) pk[r] = (__bf16)acc[nt][r];
            *(bf16x4_t*)&vo[bb * (H_ * (long)T_) + h * (long)T_ + tt] = pk;
        }
    }
}

// ---------------------------------------------------------------------------
// Flash attention, causal, transposed-score, SPLIT-K across 4 waves.
// Block = (b, 16-q-tile); wave w handles K-tiles tk0 = w*32 + j*128 with
// private online-softmax state; merge at the end via LDS.
// Inner loop identical to the verified round-3 kernel (S^T = K Q^T, stats
// in-lane + 2 shuffles, P [q][k] bf16 stride 40, O^T = V^T P^T).
// ---------------------------------------------------------------------------
__global__ __launch_bounds__(256) void attn_kernel(
    const __bf16* __restrict__ q,   // [B][T][H]
    const __bf16* __restrict__ k,   // [B][T][H]
    const __bf16* __restrict__ vT,  // [B][H][T]
    float* __restrict__ out)        // [B][T][H] fp32
{
    const int b    = blockIdx.y;
    const int q0   = (gridDim.x - 1 - blockIdx.x) * 16;   // heavy tiles first
    const int tid  = threadIdx.x;
    const int w    = tid >> 6;
    const int lane = tid & 63;
    const int m16  = lane & 15;
    const int quad = lane >> 4;
    const int koff = quad * 8;

    __shared__ __bf16 P16[4][16 * 40];      // per-wave P buffer, 5 KB
    __shared__ float  SLOT[3][32 * 64];     // [reg][lane] transposed, 24 KB
    __shared__ float  MST[4][16], LST[4][16];

    const __bf16* __restrict__ qb = q  + (long)b * T_ * H_;
    const __bf16* __restrict__ kb = k  + (long)b * T_ * H_;
    const __bf16* __restrict__ vb = vT + (long)b * H_ * T_;

    bf16x8_t qfr[4];
    #pragma unroll
    for (int s = 0; s < 4; ++s)
        qfr[s] = *(const bf16x8_t*)&qb[(q0 + m16) * H_ + s * 32 + koff];

    f32x4_t acc[8];
    #pragma unroll
    for (int i = 0; i < 8; ++i) acc[i] = f32x4_t{0, 0, 0, 0};
    float mrun = -1e30f, lrun = 0.f;

    const float SC = 0.08838834764831845f;   // 1/sqrt(128)
    const int qg = q0 + m16;
    __bf16* Pb = &P16[w][0];

    for (int tk0 = w * 32; tk0 <= q0 + 15; tk0 += 128) {
        // ---- S^T = K Q^T : two 16-krow tiles ----
        f32x4_t s0 = f32x4_t{0,0,0,0}, s1 = f32x4_t{0,0,0,0};
        #pragma unroll
        for (int s = 0; s < 4; ++s) {
            bf16x8_t k0f = *(const bf16x8_t*)&kb[(tk0      + m16) * H_ + s * 32 + koff];
            bf16x8_t k1f = *(const bf16x8_t*)&kb[(tk0 + 16 + m16) * H_ + s * 32 + koff];
            s0 = MFMA_16x16x32_BF16(k0f, qfr[s], s0);
            s1 = MFMA_16x16x32_BF16(k1f, qfr[s], s1);
        }

        // ---- mask + scale; per-q stats: in-lane + 2 shuffles ----
        float v0[4], v1[4];
        float mloc = -1e30f;
        #pragma unroll
        for (int r = 0; r < 4; ++r) {
            int kg0 = tk0 + quad * 4 + r;
            v0[r] = (kg0      <= qg) ? s0[r] * SC : -1e30f;
            v1[r] = (kg0 + 16 <= qg) ? s1[r] * SC : -1e30f;
            mloc = fmaxf(mloc, fmaxf(v0[r], v1[r]));
        }
        mloc = fmaxf(mloc, __shfl_xor(mloc, 16, 64));
        mloc = fmaxf(mloc, __shfl_xor(mloc, 32, 64));

        float mnew = fmaxf(mrun, mloc);
        float al   = __expf(mrun - mnew);
        float psum = 0.f;
        #pragma unroll
        for (int r = 0; r < 4; ++r) {
            float p0 = __expf(v0[r] - mnew);
            float p1 = __expf(v1[r] - mnew);
            psum += p0 + p1;
            Pb[m16 * 40 + quad * 4 + r]      = (__bf16)p0;
            Pb[m16 * 40 + 16 + quad * 4 + r] = (__bf16)p1;
        }
        psum += __shfl_xor(psum, 16, 64);
        psum += __shfl_xor(psum, 32, 64);
        mrun = mnew;
        lrun = lrun * al + psum;

        #pragma unroll
        for (int i = 0; i < 8; ++i)
            #pragma unroll
            for (int r = 0; r < 4; ++r)
                acc[i][r] *= al;

        bf16x8_t pa = *(const bf16x8_t*)&Pb[m16 * 40 + koff];

        #pragma unroll
        for (int i = 0; i < 8; ++i) {
            bf16x8_t vv = *(const bf16x8_t*)&vb[(i * 16 + m16) * (long)T_ + tk0 + koff];
            acc[i] = MFMA_16x16x32_BF16(vv, pa, acc[i]);
        }
    }

    // ---- split-K merge ----
    if (quad == 0) { MST[w][m16] = mrun; LST[w][m16] = lrun; }
    __syncthreads();

    float M = fmaxf(fmaxf(MST[0][m16], MST[1][m16]),
                    fmaxf(MST[2][m16], MST[3][m16]));
    float L = 0.f;
    #pragma unroll
    for (int j = 0; j < 4; ++j)
        L += LST[j][m16] * __expf(MST[j][m16] - M);

    float alpha = __expf(mrun - M);     // idle wave: exp(-inf) = 0
    #pragma unroll
    for (int i = 0; i < 8; ++i)
        #pragma unroll
        for (int r = 0; r < 4; ++r)
            acc[i][r] *= alpha;

    if (w > 0) {
        float* s = &SLOT[w - 1][0];
        #pragma unroll
        for (int i = 0; i < 8; ++i)
            #pragma unroll
            for (int r = 0; r < 4; ++r)
                s[(i * 4 + r) * 64 + lane] = acc[i][r];
    }
    __syncthreads();

    if (w == 0) {
        #pragma unroll
        for (int i = 0; i < 8; ++i)
            #pragma unroll
            for (int r = 0; r < 4; ++r)
                #pragma unroll
                for (int s = 0; s < 3; ++s)
                    acc[i][r] += SLOT[s][(i * 4 + r) * 64 + lane];

        float* __restrict__ ob = out + (long)b * T_ * H_;
        const float inv = 1.f / L;
        #pragma unroll
        for (int i = 0; i < 8; ++i) {
            f32x4_t o;
            #pragma unroll
            for (int r = 0; r < 4; ++r) o[r] = acc[i][r] * inv;
            *(f32x4_t*)&ob[(q0 + m16) * H_ + i * 16 + quad * 4] = o;
        }
    }
}

// ---------------------------------------------------------------------------
extern "C" void kernel_launch(void* const* d_in, const int* in_sizes, int n_in,
                              void* d_out, int out_size, void* d_ws, size_t ws_size,
                              hipStream_t stream)
{
    // setup_inputs order: x, Wk, Wq, Wv — all float32
    const float* x  = (const float*)d_in[0];
    const float* Wk = (const float*)d_in[1];
    const float* Wq = (const float*)d_in[2];
    const float* Wv = (const float*)d_in[3];

    // ws: q [M,H] bf16 | k [M,H] bf16 | vT [B][H][T] bf16 | WT [3][H][C] bf16
    __bf16* qws = (__bf16*)d_ws;
    __bf16* kws = qws + M_ * H_;
    __bf16* vws = kws + M_ * H_;
    __bf16* WT  = vws + (long)B_ * H_ * T_;
    float*  out = (float*)d_out;

    wt_kernel  <<<dim3(C_ / 8, 3), 128, 0, stream>>>(Wq, Wk, Wv, WT);
    proj_kernel<<<dim3((int)(M_ / 32)), 256, 0, stream>>>(x, WT, qws, kws, vws);
    attn_kernel<<<dim3(T_ / 16, B_), 256, 0, stream>>>(qws, kws, vws, out);
}

// Round 5
// 275.412 us; speedup vs baseline: 1.8975x; 1.6168x over previous
//
#include <hip/hip_runtime.h>
#include <hip/hip_bf16.h>

typedef __bf16 bf16x8_t __attribute__((ext_vector_type(8)));
typedef __bf16 bf16x4_t __attribute__((ext_vector_type(4)));
typedef float  f32x4_t  __attribute__((ext_vector_type(4)));

#define MFMA_16x16x32_BF16(A, B, C) __builtin_amdgcn_mfma_f32_16x16x32_bf16((A), (B), (C), 0, 0, 0)

static constexpr int B_ = 16;
static constexpr int T_ = 2048;
static constexpr int C_ = 1024;
static constexpr int H_ = 128;
static constexpr long M_ = (long)B_ * T_;   // 32768 rows

// ---------------------------------------------------------------------------
// W transpose: WT[z][h][c] = bf16(W_z[c][h]).  Flat: WT[n][c], n = z*128+h.
// ---------------------------------------------------------------------------
__global__ __launch_bounds__(128) void wt_kernel(
    const float* __restrict__ Wq, const float* __restrict__ Wk,
    const float* __restrict__ Wv, __bf16* __restrict__ WT)
{
    const int z = blockIdx.y;
    const float* __restrict__ W = (z == 0) ? Wq : (z == 1) ? Wk : Wv;
    const int h  = threadIdx.x;
    const int c0 = blockIdx.x * 8;
    bf16x8_t v;
    #pragma unroll
    for (int j = 0; j < 8; ++j)
        v[j] = (__bf16)W[(c0 + j) * H_ + h];
    *(bf16x8_t*)&WT[((long)z * H_ + h) * C_ + c0] = v;
}

// ---------------------------------------------------------------------------
// Fused projection. Block = 64 rows x 384 cols, 4 waves (wave w: m-tile w,
// all 24 n-tiles -> 24 MFMAs/k-step, acc 96 VGPR). x read once fp32->bf16.
// LDS ~35 KB -> 3-4 blocks/CU.
// ---------------------------------------------------------------------------
__global__ __launch_bounds__(256) void proj_kernel(
    const float*  __restrict__ x,
    const __bf16* __restrict__ WT,
    __bf16* __restrict__ qo,
    __bf16* __restrict__ ko,
    __bf16* __restrict__ vo)
{
    __shared__ __bf16 XS[64 * 40];    // [row][k]  5 KB
    __shared__ __bf16 WS[384 * 40];   // [n][k]   30 KB

    const int tid  = threadIdx.x;
    const int lane = tid & 63;
    const int w    = tid >> 6;
    const int m16  = lane & 15;
    const int quad = lane >> 4;
    const int koff = quad * 8;

    const long r0 = (long)blockIdx.x * 64;

    f32x4_t acc[24];
    #pragma unroll
    for (int nt = 0; nt < 24; ++nt) acc[nt] = f32x4_t{0, 0, 0, 0};

    for (int k0 = 0; k0 < C_; k0 += 32) {
        // stage x-tile: 64 rows x 32 k, fp32 -> bf16; 2 chunks of 16B/thread
        #pragma unroll
        for (int ch = 0; ch < 2; ++ch) {
            int s   = tid + 256 * ch;
            int row = s >> 3, c = s & 7;
            f32x4_t xv = *(const f32x4_t*)&x[(r0 + row) * C_ + k0 + c * 4];
            bf16x4_t xb;
            #pragma unroll
            for (int j = 0; j < 4; ++j) xb[j] = (__bf16)xv[j];
            *(bf16x4_t*)&XS[row * 40 + c * 4] = xb;
        }
        // stage WT-tile: 384 rows x 32 k, 6 chunks of 16B/thread
        #pragma unroll
        for (int ch = 0; ch < 6; ++ch) {
            int g = tid + 256 * ch;
            int n = g >> 2, kc = g & 3;
            *(bf16x8_t*)&WS[n * 40 + kc * 8] =
                *(const bf16x8_t*)&WT[(long)n * C_ + k0 + kc * 8];
        }
        __syncthreads();

        bf16x8_t a = *(const bf16x8_t*)&XS[(w * 16 + m16) * 40 + koff];
        #pragma unroll
        for (int nt = 0; nt < 24; ++nt) {
            bf16x8_t bfr = *(const bf16x8_t*)&WS[(nt * 16 + m16) * 40 + koff];
            acc[nt] = MFMA_16x16x32_BF16(a, bfr, acc[nt]);
        }
        __syncthreads();
    }

    // Epilogue. C/D: col = m16 (n), row = quad*4 + r (m).
    const long rbase = r0 + w * 16 + quad * 4;
    #pragma unroll
    for (int nt = 0; nt < 24; ++nt) {
        int z = nt >> 3;
        int h = (nt & 7) * 16 + m16;
        if (z < 2) {
            __bf16* __restrict__ o = z ? ko : qo;
            #pragma unroll
            for (int r = 0; r < 4; ++r)
                o[(rbase + r) * H_ + h] = (__bf16)acc[nt][r];
        } else {
            long bb = rbase >> 11, tt = rbase & 2047;   // 64 | 2048: rows stay in batch
            bf16x4_t pk;
            #pragma unroll
            for (int r = 0; r < 4; ++r) pk[r] = (__bf16)acc[nt][r];
            *(bf16x4_t*)&vo[bb * (H_ * (long)T_) + h * (long)T_ + tt] = pk;
        }
    }
}

// ---------------------------------------------------------------------------
// Flash attention, causal, transposed-score, LDS-SHARED K/V tiles.
// Block = 4 waves x 16 q-rows = 64 q-rows; one shared k-sweep in 64-wide
// tiles staged in LDS (K [64][136] pad, V^T [128][72] pad). Wave w owns
// q-tile qb*64 + w*16 fully -> no merge. Masked tail iterations for early
// waves are numerically no-ops (p=0, al=1).
// Grid 512 1-D: linear%16 = batch (XCD-pins K/V: batch b -> XCD b%8, 2 MB L2
// resident); qb decode pairs heavy+light blocks per CU (sums = 31 sweeps).
// ---------------------------------------------------------------------------
__global__ __launch_bounds__(256) void attn_kernel(
    const __bf16* __restrict__ q,   // [B][T][H]
    const __bf16* __restrict__ k,   // [B][T][H]
    const __bf16* __restrict__ vT,  // [B][H][T]
    float* __restrict__ out)        // [B][T][H] fp32
{
    __shared__ __bf16 KS[64 * 136];     // [krow][h], pad 8  (17.4 KB)
    __shared__ __bf16 VS[128 * 72];     // [h][t],    pad 8  (18.4 KB)
    __shared__ __bf16 PS[4][16 * 72];   // per-wave P [q][k], pad 8 (9.2 KB)

    const int L   = blockIdx.x;
    const int b   = L & 15;
    const int Lh  = L >> 4;                       // 0..31
    const int qb  = (Lh < 16) ? (31 - Lh) : (Lh - 16);   // heavy first, CU-paired

    const int tid  = threadIdx.x;
    const int w    = tid >> 6;
    const int lane = tid & 63;
    const int m16  = lane & 15;
    const int quad = lane >> 4;
    const int koff = quad * 8;

    const __bf16* __restrict__ qp = q  + (long)b * T_ * H_;
    const __bf16* __restrict__ kp = k  + (long)b * T_ * H_;
    const __bf16* __restrict__ vp = vT + (long)b * H_ * T_;

    const int q0w = qb * 64 + w * 16;             // wave's q-tile base
    const int qg  = q0w + m16;                    // this lane's q row

    // Q^T B-fragments (lane n=m16=q, k=h)
    bf16x8_t qfr[4];
    #pragma unroll
    for (int s = 0; s < 4; ++s)
        qfr[s] = *(const bf16x8_t*)&qp[(q0w + m16) * H_ + s * 32 + koff];

    f32x4_t acc[8];                               // O^T: row=h, col=q
    #pragma unroll
    for (int i = 0; i < 8; ++i) acc[i] = f32x4_t{0, 0, 0, 0};
    float mrun = -1e30f, lrun = 0.f;

    __bf16* Pb = &PS[w][0];
    const float SC = 0.08838834764831845f;        // 1/sqrt(128)
    const int kend = qb * 64 + 64;

    // staging coords
    const int krow = tid >> 4, kc16 = tid & 15;   // K: 16 thr/row (256B)
    const int vrow = tid >> 3, vc8  = tid & 7;    // V: 8 thr/row (128B)

    for (int tk0 = 0; tk0 < kend; tk0 += 64) {
        __syncthreads();                          // prev compute done
        #pragma unroll
        for (int ch = 0; ch < 4; ++ch) {
            int r = krow + ch * 16;
            *(bf16x8_t*)&KS[r * 136 + kc16 * 8] =
                *(const bf16x8_t*)&kp[(tk0 + r) * H_ + kc16 * 8];
        }
        #pragma unroll
        for (int ch = 0; ch < 4; ++ch) {
            int hh = vrow + ch * 32;
            *(bf16x8_t*)&VS[hh * 72 + vc8 * 8] =
                *(const bf16x8_t*)&vp[hh * (long)T_ + tk0 + vc8 * 8];
        }
        __syncthreads();                          // tiles ready

        // ---- S^T = K Q^T : 4 S-tiles of 16 k-rows ----
        f32x4_t st[4];
        #pragma unroll
        for (int kt = 0; kt < 4; ++kt) {
            f32x4_t s = f32x4_t{0, 0, 0, 0};
            #pragma unroll
            for (int sI = 0; sI < 4; ++sI) {
                bf16x8_t kf = *(const bf16x8_t*)&KS[(kt * 16 + m16) * 136 + sI * 32 + koff];
                s = MFMA_16x16x32_BF16(kf, qfr[sI], s);
            }
            st[kt] = s;
        }

        // ---- scale (+ causal mask only on boundary tiles, wave-uniform) ----
        float vv[4][4];
        if (tk0 + 63 <= q0w) {                    // fully unmasked
            #pragma unroll
            for (int kt = 0; kt < 4; ++kt)
                #pragma unroll
                for (int r = 0; r < 4; ++r)
                    vv[kt][r] = st[kt][r] * SC;
        } else {
            #pragma unroll
            for (int kt = 0; kt < 4; ++kt)
                #pragma unroll
                for (int r = 0; r < 4; ++r) {
                    int kg = tk0 + kt * 16 + quad * 4 + r;
                    vv[kt][r] = (kg <= qg) ? st[kt][r] * SC : -1e30f;
                }
        }

        float mloc = -1e30f;
        #pragma unroll
        for (int kt = 0; kt < 4; ++kt)
            #pragma unroll
            for (int r = 0; r < 4; ++r)
                mloc = fmaxf(mloc, vv[kt][r]);
        mloc = fmaxf(mloc, __shfl_xor(mloc, 16, 64));
        mloc = fmaxf(mloc, __shfl_xor(mloc, 32, 64));

        float mnew = fmaxf(mrun, mloc);
        float al   = __expf(mrun - mnew);
        float psum = 0.f;
        #pragma unroll
        for (int kt = 0; kt < 4; ++kt) {
            bf16x4_t pk;
            #pragma unroll
            for (int r = 0; r < 4; ++r) {
                float p = __expf(vv[kt][r] - mnew);
                psum += p;
                pk[r] = (__bf16)p;
            }
            *(bf16x4_t*)&Pb[m16 * 72 + kt * 16 + quad * 4] = pk;
        }
        psum += __shfl_xor(psum, 16, 64);
        psum += __shfl_xor(psum, 32, 64);
        mrun = mnew;
        lrun = lrun * al + psum;

        #pragma unroll
        for (int i = 0; i < 8; ++i)
            #pragma unroll
            for (int r = 0; r < 4; ++r)
                acc[i][r] *= al;

        // ---- O^T += V^T P^T : two K=32 halves over the 64-wide tile ----
        #pragma unroll
        for (int half = 0; half < 2; ++half) {
            bf16x8_t pa = *(const bf16x8_t*)&Pb[m16 * 72 + half * 32 + koff];
            #pragma unroll
            for (int i = 0; i < 8; ++i) {
                bf16x8_t vf = *(const bf16x8_t*)&VS[(i * 16 + m16) * 72 + half * 32 + koff];
                acc[i] = MFMA_16x16x32_BF16(vf, pa, acc[i]);
            }
        }
    }

    // ---- epilogue: O[q][h] = acc/lrun, f32x4 stores ----
    float* __restrict__ ob = out + (long)b * T_ * H_;
    const float inv = 1.f / lrun;
    #pragma unroll
    for (int i = 0; i < 8; ++i) {
        f32x4_t o;
        #pragma unroll
        for (int r = 0; r < 4; ++r) o[r] = acc[i][r] * inv;
        *(f32x4_t*)&ob[(q0w + m16) * H_ + i * 16 + quad * 4] = o;
    }
}

// ---------------------------------------------------------------------------
extern "C" void kernel_launch(void* const* d_in, const int* in_sizes, int n_in,
                              void* d_out, int out_size, void* d_ws, size_t ws_size,
                              hipStream_t stream)
{
    // setup_inputs order: x, Wk, Wq, Wv — all float32
    const float* x  = (const float*)d_in[0];
    const float* Wk = (const float*)d_in[1];
    const float* Wq = (const float*)d_in[2];
    const float* Wv = (const float*)d_in[3];

    // ws: q [M,H] bf16 | k [M,H] bf16 | vT [B][H][T] bf16 | WT [3][H][C] bf16
    __bf16* qws = (__bf16*)d_ws;
    __bf16* kws = qws + M_ * H_;
    __bf16* vws = kws + M_ * H_;
    __bf16* WT  = vws + (long)B_ * H_ * T_;
    float*  out = (float*)d_out;

    wt_kernel  <<<dim3(C_ / 8, 3), 128, 0, stream>>>(Wq, Wk, Wv, WT);
    proj_kernel<<<dim3((int)(M_ / 64)), 256, 0, stream>>>(x, WT, qws, kws, vws);
    attn_kernel<<<dim3(512), 256, 0, stream>>>(qws, kws, vws, out);
}